// Round 2
// 630.307 us; speedup vs baseline: 1.0260x; 1.0260x over previous
//
#include <hip/hip_runtime.h>

#define D_MODEL  768
#define NHEAD    12
#define HEAD_DIM 64
#define SEQ      1024
#define BATCH    8
#define NTOK     8192

typedef unsigned short u16;
typedef unsigned int   u32;
typedef float  f32x4  __attribute__((ext_vector_type(4)));
typedef __bf16 bf16x8 __attribute__((ext_vector_type(8)));

#define MFMA(a, b, c) __builtin_amdgcn_mfma_f32_16x16x32_bf16((a), (b), (c), 0, 0, 0)

__device__ __forceinline__ u16 f2bf(float f) {          // RNE float->bf16
    u32 u = __float_as_uint(f);
    u += 0x7fffu + ((u >> 16) & 1u);
    return (u16)(u >> 16);
}
__device__ __forceinline__ u32 pack2(float a, float b) {
    return (u32)f2bf(a) | ((u32)f2bf(b) << 16);
}
__device__ __forceinline__ bf16x8 ldfrag(const u16* p) { // 16B-aligned LDS read
    union { uint4 u; bf16x8 b; } c;
    c.u = *(const uint4*)p;
    return c.b;
}
__device__ __forceinline__ bf16x8 u2b(uint4 u) {
    union { uint4 u; bf16x8 b; } c;
    c.u = u;
    return c.b;
}
__device__ __forceinline__ float bflo(u32 u) { return __uint_as_float(u << 16); }
__device__ __forceinline__ float bfhi(u32 u) { return __uint_as_float(u & 0xffff0000u); }

// ---------------------------------------------------------------------------
// Kernel 1: QKV projection, bf16 MFMA.  y = x @ W^T + b.   (unchanged)
// ---------------------------------------------------------------------------
__global__ __launch_bounds__(256)
void qkv_gemm(const float* __restrict__ x,
              const float* __restrict__ Wq, const float* __restrict__ bq,
              const float* __restrict__ Wk, const float* __restrict__ bk,
              const float* __restrict__ Wv, const float* __restrict__ bv,
              u16* __restrict__ qo, u16* __restrict__ ko, u16* __restrict__ vto)
{
    const int m0 = blockIdx.x * 64;
    const int n0 = blockIdx.y * 64;
    const int z  = blockIdx.z;
    const float* W    = (z == 0) ? Wq : (z == 1) ? Wk : Wv;
    const float* bias = (z == 0) ? bq : (z == 1) ? bk : bv;

    __shared__ u16 As[64][72];
    __shared__ u16 Bs[64][72];

    const int t    = threadIdx.x;
    const int lane = t & 63, wave = t >> 6;
    const int grp  = lane >> 4, l16 = lane & 15;
    const int wm   = (wave >> 1) * 32;
    const int wn   = (wave & 1) * 32;
    const int sr   = t >> 2;
    const int sc   = (t & 3) * 16;

    f32x4 acc[2][2] = {};

    for (int kt = 0; kt < D_MODEL; kt += 64) {
        const float* xp = x + (size_t)(m0 + sr) * D_MODEL + kt + sc;
        const float* wp = W + (size_t)(n0 + sr) * D_MODEL + kt + sc;
        const float4 x0 = ((const float4*)xp)[0], x1 = ((const float4*)xp)[1];
        const float4 x2 = ((const float4*)xp)[2], x3 = ((const float4*)xp)[3];
        const float4 w0 = ((const float4*)wp)[0], w1 = ((const float4*)wp)[1];
        const float4 w2 = ((const float4*)wp)[2], w3 = ((const float4*)wp)[3];
        __syncthreads();
        uint4 ua, ub;
        ua.x = pack2(x0.x, x0.y); ua.y = pack2(x0.z, x0.w);
        ua.z = pack2(x1.x, x1.y); ua.w = pack2(x1.z, x1.w);
        ub.x = pack2(x2.x, x2.y); ub.y = pack2(x2.z, x2.w);
        ub.z = pack2(x3.x, x3.y); ub.w = pack2(x3.z, x3.w);
        *(uint4*)&As[sr][sc]     = ua;
        *(uint4*)&As[sr][sc + 8] = ub;
        ua.x = pack2(w0.x, w0.y); ua.y = pack2(w0.z, w0.w);
        ua.z = pack2(w1.x, w1.y); ua.w = pack2(w1.z, w1.w);
        ub.x = pack2(w2.x, w2.y); ub.y = pack2(w2.z, w2.w);
        ub.z = pack2(w3.x, w3.y); ub.w = pack2(w3.z, w3.w);
        *(uint4*)&Bs[sr][sc]     = ua;
        *(uint4*)&Bs[sr][sc + 8] = ub;
        __syncthreads();
#pragma unroll
        for (int ks = 0; ks < 64; ks += 32) {
            const bf16x8 a0 = ldfrag(&As[wm + l16][ks + grp * 8]);
            const bf16x8 a1 = ldfrag(&As[wm + 16 + l16][ks + grp * 8]);
            const bf16x8 b0 = ldfrag(&Bs[wn + l16][ks + grp * 8]);
            const bf16x8 b1 = ldfrag(&Bs[wn + 16 + l16][ks + grp * 8]);
            acc[0][0] = MFMA(a0, b0, acc[0][0]);
            acc[0][1] = MFMA(a0, b1, acc[0][1]);
            acc[1][0] = MFMA(a1, b0, acc[1][0]);
            acc[1][1] = MFMA(a1, b1, acc[1][1]);
        }
    }

    u16* qk_out = (z == 0) ? qo : ko;
#pragma unroll
    for (int tn = 0; tn < 2; ++tn) {
        const int col = n0 + wn + tn * 16 + l16;
        const float bcol = bias[col];
#pragma unroll
        for (int tm = 0; tm < 2; ++tm) {
#pragma unroll
            for (int r = 0; r < 4; ++r) {
                const int row = m0 + wm + tm * 16 + grp * 4 + r;
                const u16 hv = f2bf(acc[tm][tn][r] + bcol);
                if (z < 2) {
                    qk_out[(size_t)row * D_MODEL + col] = hv;
                } else {
                    const int hh = col >> 6, dd = col & 63;
                    const int bb = row >> 10, ss = row & 1023;
                    vto[(((size_t)(bb * NHEAD + hh)) * HEAD_DIM + dd) * SEQ + ss] = hv;
                }
            }
        }
    }
}

// ---------------------------------------------------------------------------
// Kernel 2: attention, single QK^T pass.
// Softmax linearity: accumulate PV with UNNORMALIZED p~ = exp(logit), scale
// accO by 1/sum at the end.  The bf16 p~ A-fragments produced by the Ps LDS
// transpose (needed for PV anyway) are saved in 128 VGPRs (row-major: each
// lane holds 8 consecutive columns of row l16 per (kt,half)).  Pass 2 is a
// pure register->global store sweep: unpack, multiply by sinv(row), dwordx4
// stores.  No second QK^T, no second exp, no second K staging, no barriers
// in pass 2.  VGPR ~210 -> 2 waves/SIMD (8/CU, 2 blocks/CU).
// ---------------------------------------------------------------------------
__global__ __launch_bounds__(256, 2)
void attn_mfma(const u16* __restrict__ qb, const u16* __restrict__ kb,
               const u16* __restrict__ vtb, float* __restrict__ hout,
               float* __restrict__ sout)
{
    const int qt = blockIdx.x, h = blockIdx.y, b = blockIdx.z;
    const int t    = threadIdx.x;
    const int lane = t & 63, wave = t >> 6;
    const int grp  = lane >> 4, l16 = lane & 15;

    __shared__ u16 Qs[64][72];
    __shared__ u16 Ks[64][72];
    __shared__ u16 Vts[64][72];
    __shared__ u16 Ps[4][16][40];

    const size_t tok0 = (size_t)b * SEQ + qt * 64;
    const int    hb   = h * HEAD_DIM;
    const int    lr   = t >> 3, c0 = (t & 7) * 8;

    // ---- stage Q (once) ----
    {
        const u16* qp = qb + (tok0 + lr) * D_MODEL + hb + c0;
        const uint4 v0 = *(const uint4*)qp;
        const uint4 v1 = *(const uint4*)(qp + (size_t)32 * D_MODEL);
        *(uint4*)&Qs[lr][c0]      = v0;
        *(uint4*)&Qs[lr + 32][c0] = v1;
    }
    __syncthreads();
    const bf16x8 qa0 = ldfrag(&Qs[wave * 16 + l16][grp * 8]);
    const bf16x8 qa1 = ldfrag(&Qs[wave * 16 + l16][32 + grp * 8]);

    const float scale = 0.125f;
    float ssum[4] = {0.f, 0.f, 0.f, 0.f};
    f32x4 accO[4] = {};
    uint4 preg[32];                 // p~ bf16, A-layout, fully unrolled indices

    const u16* kbase = kb + (size_t)b * SEQ * D_MODEL + hb;
    const u16* vbase = vtb + ((size_t)(b * NHEAD + h) * HEAD_DIM + lr) * SEQ;

    // ---- single pass: QK^T -> exp -> (save p~) -> unnormalized PV ----
#pragma unroll
    for (int kt = 0; kt < 16; ++kt) {
        __syncthreads();
        {
            const u16* kp = kbase + (size_t)(kt * 64 + lr) * D_MODEL + c0;
            const uint4 v0 = *(const uint4*)kp;
            const uint4 v1 = *(const uint4*)(kp + (size_t)32 * D_MODEL);
            const u16* vp = vbase + kt * 64 + c0;
            const uint4 u0 = *(const uint4*)vp;
            const uint4 u1 = *(const uint4*)(vp + (size_t)32 * SEQ);
            *(uint4*)&Ks[lr][c0]       = v0;
            *(uint4*)&Ks[lr + 32][c0]  = v1;
            *(uint4*)&Vts[lr][c0]      = u0;
            *(uint4*)&Vts[lr + 32][c0] = u1;
        }
        __syncthreads();
#pragma unroll
        for (int half = 0; half < 2; ++half) {
#pragma unroll
            for (int sub = 0; sub < 2; ++sub) {
                const int ti = half * 2 + sub;
                const bf16x8 kb0 = ldfrag(&Ks[ti * 16 + l16][grp * 8]);
                const bf16x8 kb1 = ldfrag(&Ks[ti * 16 + l16][32 + grp * 8]);
                f32x4 c = {0.f, 0.f, 0.f, 0.f};
                c = MFMA(qa0, kb0, c);
                c = MFMA(qa1, kb1, c);
#pragma unroll
                for (int r = 0; r < 4; ++r) {
                    const float p = __expf(c[r] * scale);   // unnormalized
                    ssum[r] += p;
                    Ps[wave][grp * 4 + r][sub * 16 + l16] = f2bf(p);
                }
            }
            // wave-private C-layout -> A-layout transpose (lgkmcnt by compiler)
            const uint4 pw = *(const uint4*)&Ps[wave][l16][grp * 8];
            preg[kt * 2 + half] = pw;                        // keep for pass 2
            const bf16x8 pa = u2b(pw);
#pragma unroll
            for (int c4 = 0; c4 < 4; ++c4) {
                const bf16x8 vb = ldfrag(&Vts[c4 * 16 + l16][half * 32 + grp * 8]);
                accO[c4] = MFMA(pa, vb, accO[c4]);
            }
        }
    }

    // ---- row sums -> sinv ----
#pragma unroll
    for (int off = 1; off < 16; off <<= 1)
#pragma unroll
        for (int r = 0; r < 4; ++r) ssum[r] += __shfl_xor(ssum[r], off);
    float sinv[4];
#pragma unroll
    for (int r = 0; r < 4; ++r) sinv[r] = 1.0f / ssum[r];

    // sinv for row l16 (A-layout rows): fetch the 4 sums of group (l16>>2),
    // then select reg (l16&3).
    const int src = (l16 >> 2) * 16 + l16;
    const float t0 = __shfl(ssum[0], src), t1 = __shfl(ssum[1], src);
    const float t2 = __shfl(ssum[2], src), t3 = __shfl(ssum[3], src);
    const float sa = (l16 & 1) ? t1 : t0;
    const float sb = (l16 & 1) ? t3 : t2;
    const float sinvrow = 1.0f / ((l16 & 2) ? sb : sa);

    // ---- h epilogue (scale unnormalized accO) ----
#pragma unroll
    for (int c4 = 0; c4 < 4; ++c4)
#pragma unroll
        for (int r = 0; r < 4; ++r)
            hout[(tok0 + wave * 16 + grp * 4 + r) * D_MODEL + hb + c4 * 16 + l16] =
                accO[c4][r] * sinv[r];

    // ---- pass 2: pure store sweep of normalized scores ----
    float* sp = sout + (size_t)(b * NHEAD + h) * SEQ * SEQ
              + (size_t)(qt * 64 + wave * 16 + l16) * SEQ + grp * 8;
#pragma unroll
    for (int kt = 0; kt < 16; ++kt) {
#pragma unroll
        for (int half = 0; half < 2; ++half) {
            const uint4 pw = preg[kt * 2 + half];
            float4 o0, o1;
            o0.x = bflo(pw.x) * sinvrow; o0.y = bfhi(pw.x) * sinvrow;
            o0.z = bflo(pw.y) * sinvrow; o0.w = bfhi(pw.y) * sinvrow;
            o1.x = bflo(pw.z) * sinvrow; o1.y = bfhi(pw.z) * sinvrow;
            o1.z = bflo(pw.w) * sinvrow; o1.w = bfhi(pw.w) * sinvrow;
            *(float4*)(sp + kt * 64 + half * 32)     = o0;
            *(float4*)(sp + kt * 64 + half * 32 + 4) = o1;
        }
    }
}

extern "C" void kernel_launch(void* const* d_in, const int* in_sizes, int n_in,
                              void* d_out, int out_size, void* d_ws, size_t ws_size,
                              hipStream_t stream)
{
    const float* x  = (const float*)d_in[0];
    const float* Wq = (const float*)d_in[1];
    const float* bq = (const float*)d_in[2];
    const float* Wk = (const float*)d_in[3];
    const float* bk = (const float*)d_in[4];
    const float* Wv = (const float*)d_in[5];
    const float* bv = (const float*)d_in[6];

    float* hout = (float*)d_out;                       // [8,1024,768]
    float* sout = hout + (size_t)NTOK * D_MODEL;       // [8,12,1024,1024]

    u16* qbuf  = (u16*)d_ws;                           // [8192][768] bf16
    u16* kbuf  = qbuf + (size_t)NTOK * D_MODEL;        // [8192][768] bf16
    u16* vtbuf = kbuf + (size_t)NTOK * D_MODEL;        // [8][12][64][1024] bf16

    qkv_gemm<<<dim3(NTOK / 64, D_MODEL / 64, 3), 256, 0, stream>>>(
        x, Wq, bq, Wk, bk, Wv, bv, qbuf, kbuf, vtbuf);
    attn_mfma<<<dim3(SEQ / 64, NHEAD, BATCH), 256, 0, stream>>>(
        qbuf, kbuf, vtbuf, hout, sout);
}